// Round 8
// baseline (810.076 us; speedup 1.0000x reference)
//
#include <hip/hip_runtime.h>
#include <hip/hip_cooperative_groups.h>
#include <stdint.h>

// VoxelLayer: JAX voxel-grid downsample ×2, bit-exact Threefry-2x32
// (partitionable) sampling. Round 8: single cooperative mega-kernel
// (256 blocks x 1024 thr x 128KB LDS = 1 block/CU), 7 grid.sync()s
// replace 7 dispatch boundaries. Fallback to atomic multi-kernel path
// if cooperative launch fails.

namespace cg = cooperative_groups;

typedef unsigned int u32;
typedef unsigned long long u64;

struct KeyArr { uint32_t k0[16]; uint32_t k1[16]; };

__host__ __device__ inline void tf2x32(uint32_t k0, uint32_t k1,
                                       uint32_t c0, uint32_t c1,
                                       uint32_t& o0, uint32_t& o1) {
  const uint32_t ks0 = k0, ks1 = k1, ks2 = k0 ^ k1 ^ 0x1BD11BDAu;
  uint32_t x0 = c0 + ks0, x1 = c1 + ks1;
#define TF_R(r) { x0 += x1; x1 = (x1 << (r)) | (x1 >> (32 - (r))); x1 ^= x0; }
  TF_R(13) TF_R(15) TF_R(26) TF_R(6)
  x0 += ks1; x1 += ks2 + 1u;
  TF_R(17) TF_R(29) TF_R(16) TF_R(24)
  x0 += ks2; x1 += ks0 + 2u;
  TF_R(13) TF_R(15) TF_R(26) TF_R(6)
  x0 += ks0; x1 += ks1 + 3u;
  TF_R(17) TF_R(29) TF_R(16) TF_R(24)
  x0 += ks1; x1 += ks2 + 4u;
  TF_R(13) TF_R(15) TF_R(26) TF_R(6)
  x0 += ks2; x1 += ks0 + 5u;
#undef TF_R
  o0 = x0; o1 = x1;
}

// Q20 fixed-point binning into LDS (order-independent -> deterministic)
#define BIN_PT(px, py, pz, SS, VOX, M0, M1, M2, LA, LB) { \
    int v0 = (int)floorf(((px) - (M0)) / (VOX)); \
    int v1 = (int)floorf(((py) - (M1)) / (VOX)); \
    int v2 = (int)floorf(((pz) - (M2)) / (VOX)); \
    int lin = (v0 * (SS) + v1) * (SS) + v2; \
    u32 qx = (u32)((px) * 1048576.0f); \
    u32 qy = (u32)((py) * 1048576.0f); \
    u32 qz = (u32)((pz) * 1048576.0f); \
    atomicAdd(&(LA)[lin], ((u64)qy << 32) | (u64)qx); \
    atomicAdd(&(LB)[lin], (1ull << 32) | (u64)qz); }

#define MN1 262144
#define ML1 131072
#define ML2 65536
#define MG1 8000
#define MG2 1000

// =================== cooperative mega-kernel ===================
__global__ __launch_bounds__(1024) void mega_kernel(
    const float* __restrict__ x, float* __restrict__ out,
    u64* __restrict__ Ap, u64* __restrict__ Bp, float4* __restrict__ means4,
    float* __restrict__ pmin1, float* __restrict__ pmin2,
    u32* __restrict__ bcnt, u32* __restrict__ numvox,
    KeyArr keys1, KeyArr keys2) {
  cg::grid_group gg = cg::this_grid();
  extern __shared__ u64 lds[];  // 16000 u64 = 128000 B
  __shared__ float s_m[3];
  float* ldsf = (float*)lds;
  u32* lds32 = (u32*)lds;
  const int k = blockIdx.x;      // 0..255
  const int b = k >> 4;          // batch
  const int c = k & 15;          // chunk / part
  const int tid = threadIdx.x, lane = tid & 63, wid = tid >> 6;

  // ---- phase 0: per-(b,coord) min of x; block (b,c) -> slice c ----
  {
    const float4* px4 = (const float4*)x;
    float4 t[12];
#pragma unroll
    for (int r = 0; r < 3; ++r) {
      const float4* p = px4 + (size_t)(b * 3 + r) * (MN1 / 4) + c * 4096 + tid;
      t[r * 4 + 0] = p[0];
      t[r * 4 + 1] = p[1024];
      t[r * 4 + 2] = p[2048];
      t[r * 4 + 3] = p[3072];
    }
#pragma unroll
    for (int r = 0; r < 3; ++r) {
      float4 a = t[r * 4], e = t[r * 4 + 1], f = t[r * 4 + 2], g = t[r * 4 + 3];
      float m = fminf(
          fminf(fminf(fminf(a.x, a.y), fminf(a.z, a.w)),
                fminf(fminf(e.x, e.y), fminf(e.z, e.w))),
          fminf(fminf(fminf(f.x, f.y), fminf(f.z, f.w)),
                fminf(fminf(g.x, g.y), fminf(g.z, g.w))));
      for (int off = 32; off; off >>= 1) m = fminf(m, __shfl_down(m, off, 64));
      if (lane == 0) ldsf[r * 16 + wid] = m;
    }
    __syncthreads();
    if (tid < 3) {
      float v = ldsf[tid * 16];
      for (int i = 1; i < 16; ++i) v = fminf(v, ldsf[tid * 16 + i]);
      pmin1[(b * 3 + tid) * 16 + c] = v;
    }
  }
  __threadfence();
  gg.sync();

  // ---- phase 1: accum layer 1 (LDS hist), write partial slice c ----
  {
    u64* lA = lds;
    u64* lB = lds + MG1;
    for (int i = tid; i < 2 * MG1; i += 1024) lds[i] = 0ull;
    if (tid < 3) {
      float v = pmin1[(b * 3 + tid) * 16];
      for (int i = 1; i < 16; ++i) v = fminf(v, pmin1[(b * 3 + tid) * 16 + i]);
      s_m[tid] = v;
    }
    __syncthreads();
    float m0 = s_m[0], m1 = s_m[1], m2 = s_m[2];
    const float* basep = x + (size_t)b * 3 * MN1;
    const float4* r0 = (const float4*)(basep + c * 16384);
    const float4* r1 = (const float4*)(basep + MN1 + c * 16384);
    const float4* r2 = (const float4*)(basep + 2 * MN1 + c * 16384);
    for (int i = tid; i < 4096; i += 1024) {
      float4 X = r0[i], Y = r1[i], Z = r2[i];
      BIN_PT(X.x, Y.x, Z.x, 20, 0.05f, m0, m1, m2, lA, lB)
      BIN_PT(X.y, Y.y, Z.y, 20, 0.05f, m0, m1, m2, lA, lB)
      BIN_PT(X.z, Y.z, Z.z, 20, 0.05f, m0, m1, m2, lA, lB)
      BIN_PT(X.w, Y.w, Z.w, 20, 0.05f, m0, m1, m2, lA, lB)
    }
    __syncthreads();
    u64* gA = Ap + ((size_t)c * 16 + b) * MG1;
    u64* gB = Bp + ((size_t)c * 16 + b) * MG1;
    for (int cell = tid; cell < MG1; cell += 1024) {
      gA[cell] = lA[cell];
      gB[cell] = lB[cell];
    }
  }
  __threadfence();
  gg.sync();

  // ---- phase 2A: reduce 16 partials; cell value stays in registers ----
  float4 cv = make_float4(0.f, 0.f, 0.f, 0.f);
  bool occ = false;
  u32 wpre = 0;
  {
    if (tid < 500) {
      int cell = c * 500 + tid;
      u64 A = 0ull, Bv = 0ull;
      for (int p = 0; p < 16; ++p) {
        size_t o = ((size_t)p * 16 + b) * MG1 + cell;
        A += Ap[o];
        Bv += Bp[o];
      }
      u32 cnt = (u32)(Bv >> 32);
      if (cnt) {
        double inv = 1.0 / (1048576.0 * (double)cnt);
        cv.x = (float)((double)(u32)A * inv);
        cv.y = (float)((double)(u32)(A >> 32) * inv);
        cv.z = (float)((double)(u32)Bv * inv);
        occ = true;
      }
    }
    u64 mask = __ballot(occ);
    wpre = (u32)__popcll(mask & ((1ull << lane) - 1ull));
    if (lane == 0) lds32[wid] = (u32)__popcll(mask);
    __syncthreads();
    if (tid == 0) {
      u32 s = 0;
      for (int w2 = 0; w2 < 16; ++w2) s += lds32[w2];
      bcnt[b * 16 + c] = s;
    }
  }
  __threadfence();
  gg.sync();

  // ---- phase 2B: cross-part prefix from bcnt, compact into means4 ----
  {
    if (tid == 0) {
      u32 base = 0;
      for (int i = 0; i < c; ++i) base += bcnt[b * 16 + i];
      u32 s = base;
      for (int w2 = 0; w2 < 16; ++w2) {
        u32 t2 = lds32[w2];   // wave totals survive in LDS across gg.sync
        lds32[16 + w2] = s;
        s += t2;
      }
      if (c == 15) numvox[b] = s;
    }
    __syncthreads();
    if (occ) means4[(size_t)b * MG1 + lds32[16 + wid] + wpre] = cv;
  }
  __threadfence();
  gg.sync();

  // ---- phase 3: sample layer 1 (8/thread) + fused layer-2 partial min ----
  {
    u32 nv = numvox[b];
    float fnv = (float)nv;
    int nvm1 = (int)nv - 1;
    uint32_t K0 = keys1.k0[b], K1 = keys1.k1[b];
    int l0 = c * 8192 + tid * 8;
    float4 mm[8];
#pragma unroll
    for (int j = 0; j < 8; ++j) {
      uint32_t w0, w1;
      tf2x32(K0, K1, 0u, (uint32_t)(l0 + j), w0, w1);
      uint32_t bits = w0 ^ w1;  // partitionable fold
      float u = __uint_as_float((bits >> 9) | 0x3F800000u) - 1.0f;
      int idx = (int)(u * fnv);  // f32 RN mul, trunc
      if (idx > nvm1) idx = nvm1;
      mm[j] = means4[(size_t)b * MG1 + idx];
    }
    float* orow = out + ((size_t)b * 3 + 0) * ML1 + l0;
    *(float4*)orow = make_float4(mm[0].x, mm[1].x, mm[2].x, mm[3].x);
    *(float4*)(orow + 4) = make_float4(mm[4].x, mm[5].x, mm[6].x, mm[7].x);
    orow = out + ((size_t)b * 3 + 1) * ML1 + l0;
    *(float4*)orow = make_float4(mm[0].y, mm[1].y, mm[2].y, mm[3].y);
    *(float4*)(orow + 4) = make_float4(mm[4].y, mm[5].y, mm[6].y, mm[7].y);
    orow = out + ((size_t)b * 3 + 2) * ML1 + l0;
    *(float4*)orow = make_float4(mm[0].z, mm[1].z, mm[2].z, mm[3].z);
    *(float4*)(orow + 4) = make_float4(mm[4].z, mm[5].z, mm[6].z, mm[7].z);
    float ax = fminf(fminf(fminf(mm[0].x, mm[1].x), fminf(mm[2].x, mm[3].x)),
                     fminf(fminf(mm[4].x, mm[5].x), fminf(mm[6].x, mm[7].x)));
    float ay = fminf(fminf(fminf(mm[0].y, mm[1].y), fminf(mm[2].y, mm[3].y)),
                     fminf(fminf(mm[4].y, mm[5].y), fminf(mm[6].y, mm[7].y)));
    float az = fminf(fminf(fminf(mm[0].z, mm[1].z), fminf(mm[2].z, mm[3].z)),
                     fminf(fminf(mm[4].z, mm[5].z), fminf(mm[6].z, mm[7].z)));
    for (int off = 32; off; off >>= 1) {
      ax = fminf(ax, __shfl_down(ax, off, 64));
      ay = fminf(ay, __shfl_down(ay, off, 64));
      az = fminf(az, __shfl_down(az, off, 64));
    }
    if (lane == 0) {
      ldsf[0 * 16 + wid] = ax;
      ldsf[1 * 16 + wid] = ay;
      ldsf[2 * 16 + wid] = az;
    }
    __syncthreads();
    if (tid < 3) {
      float v = ldsf[tid * 16];
      for (int i = 1; i < 16; ++i) v = fminf(v, ldsf[tid * 16 + i]);
      pmin2[(b * 3 + tid) * 16 + c] = v;
    }
  }
  __threadfence();
  gg.sync();

  // ---- phase 4: accum layer 2 on out1, write partial slice c ----
  {
    u64* lA = lds;
    u64* lB = lds + MG2;
    for (int i = tid; i < 2 * MG2; i += 1024) lds[i] = 0ull;
    if (tid < 3) {
      float v = pmin2[(b * 3 + tid) * 16];
      for (int i = 1; i < 16; ++i) v = fminf(v, pmin2[(b * 3 + tid) * 16 + i]);
      s_m[tid] = v;
    }
    __syncthreads();
    float m0 = s_m[0], m1 = s_m[1], m2 = s_m[2];
    const float* basep = out + (size_t)b * 3 * ML1;
    const float4* r0 = (const float4*)(basep + c * 8192);
    const float4* r1 = (const float4*)(basep + ML1 + c * 8192);
    const float4* r2 = (const float4*)(basep + 2 * ML1 + c * 8192);
    for (int i = tid; i < 2048; i += 1024) {
      float4 X = r0[i], Y = r1[i], Z = r2[i];
      BIN_PT(X.x, Y.x, Z.x, 10, 0.1f, m0, m1, m2, lA, lB)
      BIN_PT(X.y, Y.y, Z.y, 10, 0.1f, m0, m1, m2, lA, lB)
      BIN_PT(X.z, Y.z, Z.z, 10, 0.1f, m0, m1, m2, lA, lB)
      BIN_PT(X.w, Y.w, Z.w, 10, 0.1f, m0, m1, m2, lA, lB)
    }
    __syncthreads();
    u64* gA = Ap + ((size_t)c * 16 + b) * MG2;
    u64* gB = Bp + ((size_t)c * 16 + b) * MG2;
    for (int cell = tid; cell < MG2; cell += 1024) {
      gA[cell] = lA[cell];
      gB[cell] = lB[cell];
    }
  }
  __threadfence();
  gg.sync();

  // ---- phase 5: fused reduce+compact layer 2 (blocks 0..15) ----
  if (k < 16) {
    int b2 = k;
    float4 v2 = make_float4(0.f, 0.f, 0.f, 0.f);
    bool occ2 = false;
    if (tid < MG2) {
      u64 A = 0ull, Bv = 0ull;
      for (int p = 0; p < 16; ++p) {
        size_t o = ((size_t)p * 16 + b2) * MG2 + tid;
        A += Ap[o];
        Bv += Bp[o];
      }
      u32 cnt = (u32)(Bv >> 32);
      if (cnt) {
        double inv = 1.0 / (1048576.0 * (double)cnt);
        v2.x = (float)((double)(u32)A * inv);
        v2.y = (float)((double)(u32)(A >> 32) * inv);
        v2.z = (float)((double)(u32)Bv * inv);
        occ2 = true;
      }
    }
    u64 mask = __ballot(occ2);
    u32 wp2 = (u32)__popcll(mask & ((1ull << lane) - 1ull));
    if (lane == 0) lds32[wid] = (u32)__popcll(mask);
    __syncthreads();
    if (tid == 0) {
      u32 s = 0;
      for (int w2 = 0; w2 < 16; ++w2) {
        u32 t2 = lds32[w2];
        lds32[16 + w2] = s;
        s += t2;
      }
      numvox[16 + b2] = s;
    }
    __syncthreads();
    if (occ2) means4[(size_t)b2 * MG2 + lds32[16 + wid] + wp2] = v2;
  }
  __threadfence();
  gg.sync();

  // ---- phase 6: sample layer 2 (4/thread) ----
  {
    u32 nv = numvox[16 + b];
    float fnv = (float)nv;
    int nvm1 = (int)nv - 1;
    uint32_t K0 = keys2.k0[b], K1 = keys2.k1[b];
    int l0 = c * 4096 + tid * 4;
    float4 mm[4];
#pragma unroll
    for (int j = 0; j < 4; ++j) {
      uint32_t w0, w1;
      tf2x32(K0, K1, 0u, (uint32_t)(l0 + j), w0, w1);
      uint32_t bits = w0 ^ w1;
      float u = __uint_as_float((bits >> 9) | 0x3F800000u) - 1.0f;
      int idx = (int)(u * fnv);
      if (idx > nvm1) idx = nvm1;
      mm[j] = means4[(size_t)b * MG2 + idx];
    }
    float* o2 = out + (size_t)48 * ML1;
    *(float4*)(o2 + ((size_t)b * 3 + 0) * ML2 + l0) =
        make_float4(mm[0].x, mm[1].x, mm[2].x, mm[3].x);
    *(float4*)(o2 + ((size_t)b * 3 + 1) * ML2 + l0) =
        make_float4(mm[0].y, mm[1].y, mm[2].y, mm[3].y);
    *(float4*)(o2 + ((size_t)b * 3 + 2) * ML2 + l0) =
        make_float4(mm[0].z, mm[1].z, mm[2].z, mm[3].z);
  }
}

// =================== fallback multi-kernel path (atomic merge) ===================
__global__ void init_kernel(u64* cellsA, u64* cellsB, int ncells) {
  int i = blockIdx.x * blockDim.x + threadIdx.x;
  int stride = gridDim.x * blockDim.x;
  for (int j = i; j < ncells; j += stride) { cellsA[j] = 0ull; cellsB[j] = 0ull; }
}

__global__ void min_kernel(const float* __restrict__ in, int n4,
                           float* __restrict__ pmin) {
  int row = blockIdx.y;
  int PB = gridDim.x;
  const float4* p = (const float4*)in + (size_t)row * n4;
  int base = blockIdx.x * 2048 + threadIdx.x;
  float4 v0 = p[base], v1 = p[base + 256], v2 = p[base + 512],
         v3 = p[base + 768], v4 = p[base + 1024], v5 = p[base + 1280],
         v6 = p[base + 1536], v7 = p[base + 1792];
  float m0 = fminf(fminf(v0.x, v0.y), fminf(v0.z, v0.w));
  float m1 = fminf(fminf(v1.x, v1.y), fminf(v1.z, v1.w));
  float m2 = fminf(fminf(v2.x, v2.y), fminf(v2.z, v2.w));
  float m3 = fminf(fminf(v3.x, v3.y), fminf(v3.z, v3.w));
  float m4 = fminf(fminf(v4.x, v4.y), fminf(v4.z, v4.w));
  float m5 = fminf(fminf(v5.x, v5.y), fminf(v5.z, v5.w));
  float m6 = fminf(fminf(v6.x, v6.y), fminf(v6.z, v6.w));
  float m7 = fminf(fminf(v7.x, v7.y), fminf(v7.z, v7.w));
  float m = fminf(fminf(fminf(m0, m1), fminf(m2, m3)),
                  fminf(fminf(m4, m5), fminf(m6, m7)));
  for (int off = 32; off > 0; off >>= 1)
    m = fminf(m, __shfl_down(m, off, 64));
  __shared__ float wmin[4];
  int wid = threadIdx.x >> 6;
  if ((threadIdx.x & 63) == 0) wmin[wid] = m;
  __syncthreads();
  if (threadIdx.x == 0)
    pmin[row * PB + blockIdx.x] =
        fminf(fminf(wmin[0], wmin[1]), fminf(wmin[2], wmin[3]));
}

template <int G, int S>
__global__ __launch_bounds__(1024) void accum_atomic_kernel(
    const float* __restrict__ in, int N, float vox,
    const float* __restrict__ pmin, int PB, u64* __restrict__ Ap,
    u64* __restrict__ Bp) {
  extern __shared__ u64 lds[];
  u64* lA = lds;
  u64* lB = lds + G;
  __shared__ float s_m[3];
  int tid = threadIdx.x, b = blockIdx.y;
  for (int i = tid; i < G; i += 1024) { lA[i] = 0ull; lB[i] = 0ull; }
  int wid = tid >> 6, lane = tid & 63;
  if (wid < 3) {
    float v = __int_as_float(0x7F800000);
    for (int j = lane; j < PB; j += 64)
      v = fminf(v, pmin[(b * 3 + wid) * PB + j]);
    for (int off = 32; off > 0; off >>= 1)
      v = fminf(v, __shfl_down(v, off, 64));
    if (lane == 0) s_m[wid] = v;
  }
  __syncthreads();
  float m0 = s_m[0], m1 = s_m[1], m2 = s_m[2];
  int ppb = N / gridDim.x;
  const float* base = in + (size_t)b * 3 * N;
  int start = blockIdx.x * ppb;
  const float4* r0 = (const float4*)(base + start);
  const float4* r1 = (const float4*)(base + N + start);
  const float4* r2 = (const float4*)(base + 2 * N + start);
  int q4 = ppb >> 2;
  for (int i = tid; i < q4; i += 1024) {
    float4 X = r0[i], Y = r1[i], Z = r2[i];
    BIN_PT(X.x, Y.x, Z.x, S, vox, m0, m1, m2, lA, lB)
    BIN_PT(X.y, Y.y, Z.y, S, vox, m0, m1, m2, lA, lB)
    BIN_PT(X.z, Y.z, Z.z, S, vox, m0, m1, m2, lA, lB)
    BIN_PT(X.w, Y.w, Z.w, S, vox, m0, m1, m2, lA, lB)
  }
  __syncthreads();
  u64* gA = Ap + (size_t)b * G;
  u64* gB = Bp + (size_t)b * G;
  for (int cell = tid; cell < G; cell += 1024) {
    u64 Bv = lB[cell];
    if (Bv) { atomicAdd(&gA[cell], lA[cell]); atomicAdd(&gB[cell], Bv); }
  }
}

__global__ __launch_bounds__(1024) void compact_kernel(
    int G, const u64* __restrict__ Ac, const u64* __restrict__ Bc,
    float4* __restrict__ means4, u32* __restrict__ numvox) {
  int b = blockIdx.x, tid = threadIdx.x, wid = tid >> 6, lane = tid & 63;
  __shared__ u32 wtot[16], wbase[16];
  __shared__ u32 gbase;
  if (tid == 0) gbase = 0u;
  __syncthreads();
  for (int t0 = 0; t0 < G; t0 += 1024) {
    int cell = t0 + tid;
    float4 v = make_float4(0.f, 0.f, 0.f, 0.f);
    u32 cnt = 0u;
    if (cell < G) {
      u64 A = Ac[(size_t)b * G + cell], Bv = Bc[(size_t)b * G + cell];
      cnt = (u32)(Bv >> 32);
      if (cnt) {
        double inv = 1.0 / (1048576.0 * (double)cnt);
        v.x = (float)((double)(u32)A * inv);
        v.y = (float)((double)(u32)(A >> 32) * inv);
        v.z = (float)((double)(u32)Bv * inv);
      }
    }
    bool occ = cnt > 0u;
    u64 mask = __ballot(occ);
    u32 prefix = (u32)__popcll(mask & ((1ull << lane) - 1ull));
    if (lane == 0) wtot[wid] = (u32)__popcll(mask);
    __syncthreads();
    if (tid == 0) {
      u32 s = gbase;
      for (int w = 0; w < 16; ++w) { wbase[w] = s; s += wtot[w]; }
      gbase = s;
    }
    __syncthreads();
    if (occ) means4[(size_t)b * G + wbase[wid] + prefix] = v;
    __syncthreads();
  }
  if (tid == 0) numvox[b] = gbase;
}

__global__ void sample_kernel(int L, int G, const float4* __restrict__ means4,
                              const u32* __restrict__ numvox, KeyArr keys,
                              float* __restrict__ out) {
  int t = blockIdx.x * 256 + threadIdx.x;
  int b = blockIdx.y;
  int l0 = t * 4;
  u32 nv = numvox[b];
  float fnv = (float)nv;
  int nvm1 = (int)nv - 1;
  uint32_t K0 = keys.k0[b], K1 = keys.k1[b];
  float4 m[4];
#pragma unroll
  for (int j = 0; j < 4; ++j) {
    uint32_t w0, w1;
    tf2x32(K0, K1, 0u, (uint32_t)(l0 + j), w0, w1);
    uint32_t bits = w0 ^ w1;
    float u = __uint_as_float((bits >> 9) | 0x3F800000u) - 1.0f;
    int idx = (int)(u * fnv);
    if (idx > nvm1) idx = nvm1;
    m[j] = means4[(size_t)b * G + idx];
  }
  *(float4*)(out + ((size_t)b * 3 + 0) * L + l0) =
      make_float4(m[0].x, m[1].x, m[2].x, m[3].x);
  *(float4*)(out + ((size_t)b * 3 + 1) * L + l0) =
      make_float4(m[0].y, m[1].y, m[2].y, m[3].y);
  *(float4*)(out + ((size_t)b * 3 + 2) * L + l0) =
      make_float4(m[0].z, m[1].z, m[2].z, m[3].z);
}

extern "C" void kernel_launch(void* const* d_in, const int* in_sizes, int n_in,
                              void* d_out, int out_size, void* d_ws,
                              size_t ws_size, hipStream_t stream) {
  const float* x = (const float*)d_in[0];
  float* out = (float*)d_out;

  // ---- JAX key derivation (threefry partitionable split) ----
  uint32_t k1a, k1b, k2a, k2b;
  tf2x32(0u, 42u, 0u, 0u, k1a, k1b);
  tf2x32(0u, 42u, 0u, 1u, k2a, k2b);
  KeyArr keys1, keys2;
  for (int b = 0; b < 16; ++b) {
    tf2x32(k1a, k1b, 0u, (uint32_t)b, keys1.k0[b], keys1.k1[b]);
    tf2x32(k2a, k2b, 0u, (uint32_t)b, keys2.k0[b], keys2.k1[b]);
  }

  const size_t partsz = (size_t)16 * 16 * MG1;          // u64 per partial array
  const size_t m4cnt = (size_t)16 * MG1;                // float4 in means4
  const size_t tailBytes = (48 * 32 + 48 * 32 + 256 + 32) * 4;
  const size_t bigNeed = 2 * partsz * 8 + m4cnt * 16 + tailBytes;

  uint8_t* w = (uint8_t*)d_ws;
  bool big = ws_size >= bigNeed;

  if (big) {
    u64* Ap = (u64*)w;
    u64* Bp = Ap + partsz;
    float4* means4 = (float4*)(Bp + partsz);
    float* pmin1 = (float*)(means4 + m4cnt);
    float* pmin2 = pmin1 + 48 * 32;
    u32* bcnt = (u32*)(pmin2 + 48 * 32);
    u32* numvox = bcnt + 256;
    void* args[] = {(void*)&x,     (void*)&out,   (void*)&Ap,
                    (void*)&Bp,    (void*)&means4, (void*)&pmin1,
                    (void*)&pmin2, (void*)&bcnt,  (void*)&numvox,
                    (void*)&keys1, (void*)&keys2};
    hipError_t e = hipLaunchCooperativeKernel(
        (const void*)mega_kernel, dim3(256), dim3(1024), args, 128000, stream);
    if (e == hipSuccess) return;
    // else fall through to the non-cooperative path below
  }

  // ---- fallback: atomic-merge multi-kernel path (proven, slower) ----
  const size_t slice1 = (size_t)16 * MG1, slice2 = (size_t)16 * MG2;
  u64* As = (u64*)w;
  u64* Bs = As + (slice1 + slice2);
  float4* means4s = (float4*)(Bs + (slice1 + slice2));
  float* pmin1s = (float*)(means4s + slice1);
  float* pmin2s = pmin1s + 48 * 32;
  u32* numvoxs = (u32*)(pmin2s + 48 * 16);

  init_kernel<<<dim3(64), dim3(256), 0, stream>>>(As, Bs,
                                                  (int)(slice1 + slice2));
  min_kernel<<<dim3(32, 48), dim3(256), 0, stream>>>(x, MN1 / 4, pmin1s);
  accum_atomic_kernel<MG1, 20>
      <<<dim3(8, 16), dim3(1024), 2 * MG1 * 8, stream>>>(x, MN1, 0.05f, pmin1s,
                                                         32, As, Bs);
  compact_kernel<<<dim3(16), dim3(1024), 0, stream>>>(MG1, As, Bs, means4s,
                                                      numvoxs);
  sample_kernel<<<dim3(ML1 / 1024, 16), dim3(256), 0, stream>>>(
      ML1, MG1, means4s, numvoxs, keys1, out);
  float* out2 = out + (size_t)48 * ML1;
  min_kernel<<<dim3(16, 48), dim3(256), 0, stream>>>(out, ML1 / 4, pmin2s);
  accum_atomic_kernel<MG2, 10>
      <<<dim3(8, 16), dim3(1024), 2 * MG2 * 8, stream>>>(
          out, ML1, 0.1f, pmin2s, 16, As + slice1, Bs + slice1);
  compact_kernel<<<dim3(16), dim3(1024), 0, stream>>>(
      MG2, As + slice1, Bs + slice1, means4s, numvoxs + 16);
  sample_kernel<<<dim3(ML2 / 1024, 16), dim3(256), 0, stream>>>(
      ML2, MG2, means4s, numvoxs + 16, keys2, out2);
}